// Round 2
// baseline (76.500 us; speedup 1.0000x reference)
//
#include <hip/hip_runtime.h>
#include <stdint.h>

constexpr int BATCH = 16384;
constexpr int A     = 50;
constexpr int NN    = 51;   // A + 1
constexpr int DD    = 4;
constexpr int MAXR  = 16;
constexpr int WPB   = 4;    // waves per block (block = 256 threads)

// ---------------- Kernel A: tree construction ----------------
// One wave per element. lnf/nnv are wave-uniform 51-bit SALU masks;
// lane l holds Tree[l], ring_idx[l][0/1], edge[b][l][:]+1.
__global__ __launch_bounds__(WPB * 64)
void tree_kernel(const int* __restrict__ edge, int* __restrict__ out)
{
    const int lane = threadIdx.x & 63;
    const int wid  = threadIdx.x >> 6;
    const int b    = blockIdx.x * WPB + wid;

    int* out_tree = out + (size_t)b * NN;                            // (B,51)
    int* out_ridx = out + (size_t)BATCH * NN + (size_t)b * (NN * 2); // (B,51,2)

    int e0 = 0, e1 = 0, e2 = 0, e3 = 0;
    if (lane < A) {
        const int4 ev = *reinterpret_cast<const int4*>(edge + ((size_t)b * A + lane) * DD);
        e0 = ev.x + 1; e1 = ev.y + 1; e2 = ev.z + 1; e3 = ev.w + 1;  // me = edge+1
    }

    uint64_t L = (((uint64_t)1 << NN) - 1) & ~(uint64_t)3;  // lnf: bits 0,1 cleared
    uint64_t V = (((uint64_t)1 << NN) - 1) & ~(uint64_t)1;  // nnv: bit 0 cleared

    int tree  = 0;            // lane l: Tree[l]
    int ring0 = 0, ring1 = 0; // lane l: ring_idx[l][0/1]
    int num_rings = 0;        // wave-uniform
    int visiting  = 1;

    for (int it = 0; it < A; ++it) {
        const int vm1 = visiting - 1;
        const int n0 = __builtin_amdgcn_readlane(e0, vm1);
        const int n1 = __builtin_amdgcn_readlane(e1, vm1);
        const int n2 = __builtin_amdgcn_readlane(e2, vm1);
        const int n3 = __builtin_amdgcn_readlane(e3, vm1);
        #pragma unroll
        for (int d = 0; d < DD; ++d) {
            const int nxt = (d == 0) ? n0 : (d == 1) ? n1 : (d == 2) ? n2 : n3;
            const uint64_t bit = (uint64_t)1 << nxt;
            const bool slnf = (L & bit) != 0;
            const bool slnv = (V & bit) != 0;
            const bool cyc  = (!slnf) && slnv && (nxt != 0);
            if (cyc) {
                if (num_rings < NN && lane == num_rings) { ring0 += visiting; ring1 += nxt; }
                num_rings++;
            }
            if (slnf && lane == nxt) tree = visiting;
            L &= ~bit;
        }
        V &= ~((uint64_t)1 << visiting);
        const uint64_t M = V & ~L;
        if (M == 0) break;
        visiting = (int)__builtin_ctzll(M);
    }

    if (lane < NN) {
        out_tree[lane] = tree;
        reinterpret_cast<int2*>(out_ridx)[lane] = make_int2(ring0, ring1);
    }
}

// ---------------- Kernel B: ring reconstruction ----------------
// One wave per (element, ring slot). Paths via pointer doubling:
// lane k holds Tree^k(s0) and Tree^k(s1). Membership via LDS flags.
// Row = [path1[0..t], s0, path0[1..u-1]] where
//   t = first k with path1[k] in set(path0),
//   u = first k with path0[k] in set(path1).
__global__ __launch_bounds__(WPB * 64)
void rings_kernel(int* __restrict__ out)
{
    const int lane = threadIdx.x & 63;
    const int wid  = threadIdx.x >> 6;
    const int w    = blockIdx.x * WPB + wid;  // 0 .. BATCH*MAXR-1
    const int b    = w >> 4;
    const int i    = w & (MAXR - 1);

    __shared__ int fl0[WPB][64];
    __shared__ int fl1[WPB][64];

    int* out_rings = out + (size_t)BATCH * NN * 3 + (size_t)b * (MAXR * A) + i * A;

    const int* ridx_row = out + (size_t)BATCH * NN + (size_t)b * (NN * 2);
    const int2 rid = *reinterpret_cast<const int2*>(ridx_row + 2 * i);
    const int s0 = rid.x, s1 = rid.y;

    int rowval = 0;
    if (s0 != 0) {  // slot i is a real ring  <=>  i < num_rings[b]
        const int* tree_row = out + (size_t)b * NN;
        int f = (lane < NN) ? tree_row[lane] : 0;  // lane l: Tree[l]

        // pointer doubling: p = Tree^lane(s)
        int p0 = s0, p1 = s1;
        int g = f;  // g[l] = Tree^(2^j)[l]
        #pragma unroll
        for (int j = 0; j < 6; ++j) {
            const int t0 = __shfl(g, p0);
            const int t1 = __shfl(g, p1);
            const bool apply = (lane >> j) & 1;
            p0 = apply ? t0 : p0;
            p1 = apply ? t1 : p1;
            if (j < 5) g = __shfl(g, g);
        }

        // membership flags in LDS (same-wave ordering; compiler inserts lgkmcnt)
        fl0[wid][lane] = 0;
        fl1[wid][lane] = 0;
        fl0[wid][p0] = 1;
        fl1[wid][p1] = 1;
        const int in0 = fl0[wid][p1];  // path1[lane] in set(path0)?
        const int in1 = fl1[wid][p0];  // path0[lane] in set(path1)?

        const uint64_t bal0 = __ballot(in0 != 0);  // nonzero: path1[50]=0, 0 in set(path0)
        const uint64_t bal1 = __ballot(in1 != 0);
        const int t = (int)__builtin_ctzll(bal0);
        const int u = (int)__builtin_ctzll(bal1);

        const int pv = __shfl(p0, (lane - t - 1) & 63);  // path0[lane - t - 1]
        rowval = (lane <= t)     ? p1
               : (lane == t + 1) ? s0
               : (lane <= t + u) ? pv
               :                   0;
    }
    if (lane < A) out_rings[lane] = rowval - 1;  // untouched slots -> -1
}

extern "C" void kernel_launch(void* const* d_in, const int* in_sizes, int n_in,
                              void* d_out, int out_size, void* d_ws, size_t ws_size,
                              hipStream_t stream) {
    const int* edge = (const int*)d_in[0];
    int* out = (int*)d_out;

    dim3 block(WPB * 64);
    hipLaunchKernelGGL(tree_kernel, dim3(BATCH / WPB), block, 0, stream, edge, out);
    hipLaunchKernelGGL(rings_kernel, dim3(BATCH * MAXR / WPB), block, 0, stream, out);
}

// Round 3
// 47.865 us; speedup vs baseline: 1.5982x; 1.5982x over previous
//
#include <hip/hip_runtime.h>
#include <stdint.h>

constexpr int BATCH = 16384;
constexpr int A     = 50;
constexpr int NN    = 51;   // A + 1
constexpr int MAXR  = 16;
constexpr int EPB   = 64;   // elements per block in tree kernel (= lanes)
constexpr int WPB   = 4;    // waves per block in rings kernel

// ---------------- Kernel A: per-lane tree construction ----------------
// lane = element. lnf/nnv are per-lane uint64 VGPR bitmasks. Edge row for the
// current visit is one ds_read_b32 of a byte-packed word. Tree/ring_idx are
// per-lane byte rows in LDS (write-only during build), dumped coalesced.
__global__ __launch_bounds__(64)
void tree_kernel(const int* __restrict__ edge, int* __restrict__ out)
{
    const int lane  = threadIdx.x;
    const int bbase = blockIdx.x * EPB;

    __shared__ uint32_t eds[EPB][NN];   // [e][n]: packed me[e][n+1][0..3], stride 51 words (19 coprime 32)
    __shared__ uint8_t  tre[EPB][52];   // Tree values 0..50 as bytes
    __shared__ uint8_t  rg [EPB][104];  // ring_idx: 51 slots x 2 bytes (pad to 104)

    // zero tre, rg
    {
        uint32_t* t32 = (uint32_t*)&tre[0][0];
        for (int f = lane; f < EPB * 52 / 4; f += 64) t32[f] = 0;
        uint32_t* r32 = (uint32_t*)&rg[0][0];
        for (int f = lane; f < EPB * 104 / 4; f += 64) r32[f] = 0;
    }
    // stage + pack edges: 64*50 int4s, coalesced global reads
    {
        const int4* e4 = (const int4*)edge + (size_t)bbase * A;
        for (int k = 0; k < A; ++k) {
            const int g = k * 64 + lane;          // 0..3199
            const int4 v = e4[g];
            const int e = g / A;                  // magic-mul division
            const int n = g - A * e;
            eds[e][n] = (uint32_t)(v.x + 1) | ((uint32_t)(v.y + 1) << 8)
                      | ((uint32_t)(v.z + 1) << 16) | ((uint32_t)(v.w + 1) << 24);
        }
    }
    __syncthreads();  // single wave; cheap

    const uint64_t FULL = ((uint64_t)1 << NN) - 1;
    uint64_t L = FULL & ~(uint64_t)3;  // lnf: bits 0,1 cleared
    uint64_t V = FULL & ~(uint64_t)1;  // nnv: bit 0 cleared
    int visiting = 1;
    int nr = 0;
    bool done = false;

    for (int it = 0; it < A; ++it) {
        if (!done) {
            const uint32_t w = eds[lane][visiting - 1];
            #pragma unroll
            for (int d = 0; d < 4; ++d) {
                const int nxt = (w >> (8 * d)) & 0xff;
                const uint64_t bit = (uint64_t)1 << nxt;
                const bool slnf = (L & bit) != 0;
                const bool slnv = (V & bit) != 0;
                if (!slnf && slnv && nxt != 0) {          // cycle edge
                    if (nr < NN)                           // scatter dropped at >= 51
                        *(uint16_t*)&rg[lane][2 * nr] = (uint16_t)(visiting | (nxt << 8));
                    nr++;
                }
                if (slnf) tre[lane][nxt] = (uint8_t)visiting;  // set-once
                L &= ~bit;
            }
            V &= ~((uint64_t)1 << visiting);
            const uint64_t M = V & ~L;
            if (M == 0) done = true;
            else visiting = (int)__builtin_ctzll(M);
        }
        if (__ballot(!done) == 0) break;
    }
    __syncthreads();

    // dump Tree: 64*51 ints, coalesced
    int* otree = out + (size_t)bbase * NN;
    for (int k = 0; k < NN; ++k) {
        const int f = k * 64 + lane;              // 0..3263
        const int e = f / NN, n = f - NN * e;
        otree[f] = tre[e][n];
    }
    // dump ring_idx: (B,51,2) as int2 per slot, coalesced
    int2* oridx = (int2*)(out + (size_t)BATCH * NN) + (size_t)bbase * NN;
    for (int k = 0; k < NN; ++k) {
        const int f = k * 64 + lane;
        const int e = f / NN, i = f - NN * e;
        const uint16_t pv = *(const uint16_t*)&rg[e][2 * i];
        oridx[f] = make_int2(pv & 0xff, pv >> 8);
    }
}

// ---------------- Kernel B: ring reconstruction, wave per element ----------------
// Ancestor-doubling tables anc[j][l] = Tree^(2^j)(l) computed once per element
// (5 dependent shuffles), shared by all <=16 ring slots. Per-slot membership /
// ballot / row-compose formulas are verbatim from the verified round-2 kernel.
__global__ __launch_bounds__(WPB * 64)
void rings_kernel(int* __restrict__ out)
{
    const int lane = threadIdx.x & 63;
    const int wid  = threadIdx.x >> 6;
    const int b    = blockIdx.x * WPB + wid;

    __shared__ int fl0[WPB][64];
    __shared__ int fl1[WPB][64];

    const int*  tree_row = out + (size_t)b * NN;
    const int2* ridx_row = (const int2*)(out + (size_t)BATCH * NN) + (size_t)b * NN;
    int* orings = out + (size_t)BATCH * NN * 3 + (size_t)b * (MAXR * A);

    const int f = (lane < NN) ? tree_row[lane] : 0;   // lane l: Tree[l]
    int2 rid = make_int2(0, 0);
    if (lane < MAXR) rid = ridx_row[lane];

    // doubling tables (values always <= 50)
    int anc[6];
    anc[0] = f;
    #pragma unroll
    for (int j = 1; j < 6; ++j) anc[j] = __shfl(anc[j - 1], anc[j - 1]);

    // active slots are a prefix; count them
    const uint64_t actb = __ballot(lane < MAXR && rid.x != 0);
    const int nact = __popcll(actb);

    for (int i = 0; i < MAXR; ++i) {
        int rowval = 0;
        if (i < nact) {
            const int s0 = __shfl(rid.x, i);
            const int s1 = __shfl(rid.y, i);

            // p0/p1[lane] = Tree^lane(s0/s1)
            int p0 = s0, p1 = s1;
            #pragma unroll
            for (int j = 0; j < 6; ++j) {
                const int t0 = __shfl(anc[j], p0);
                const int t1 = __shfl(anc[j], p1);
                const bool ap = (lane >> j) & 1;
                p0 = ap ? t0 : p0;
                p1 = ap ? t1 : p1;
            }

            // membership flags (same-wave LDS ordering)
            fl0[wid][lane] = 0;
            fl1[wid][lane] = 0;
            fl0[wid][p0] = 1;
            fl1[wid][p1] = 1;
            const int in0 = fl0[wid][p1];   // path1[lane] in set(path0)?
            const int in1 = fl1[wid][p0];   // path0[lane] in set(path1)?

            const uint64_t bal0 = __ballot(in0 != 0);
            const uint64_t bal1 = __ballot(in1 != 0);
            const int t = (int)__builtin_ctzll(bal0);
            const int u = (int)__builtin_ctzll(bal1);

            const int pv = __shfl(p0, (lane - t - 1) & 63);
            rowval = (lane <= t)     ? p1
                   : (lane == t + 1) ? s0
                   : (lane <= t + u) ? pv
                   :                   0;
        }
        if (lane < A) orings[i * A + lane] = rowval - 1;  // inactive rows -> -1
    }
}

extern "C" void kernel_launch(void* const* d_in, const int* in_sizes, int n_in,
                              void* d_out, int out_size, void* d_ws, size_t ws_size,
                              hipStream_t stream) {
    const int* edge = (const int*)d_in[0];
    int* out = (int*)d_out;

    hipLaunchKernelGGL(tree_kernel, dim3(BATCH / EPB), dim3(64), 0, stream, edge, out);
    hipLaunchKernelGGL(rings_kernel, dim3(BATCH / WPB), dim3(WPB * 64), 0, stream, out);
}

// Round 4
// 42.654 us; speedup vs baseline: 1.7935x; 1.1222x over previous
//
#include <hip/hip_runtime.h>
#include <stdint.h>

constexpr int BATCH = 16384;
constexpr int A     = 50;
constexpr int NN    = 51;   // A + 1
constexpr int MAXR  = 16;
constexpr int EPB   = 64;   // elements per block (= lanes) in tree kernel
constexpr int WPB   = 4;    // waves per block in rings kernel

// ---------------- Kernel A: per-lane tree construction ----------------
// lane = element. lnf/nnv are per-lane uint64 VGPR bitmasks. The 4 edges of a
// visit are processed with PARALLEL found/dup logic (no serial L dependency);
// predicated-off LDS stores go to per-row trash slots via cndmask'd addresses.
__global__ __launch_bounds__(64)
void tree_kernel(const int* __restrict__ edge, int* __restrict__ out)
{
    const int lane  = threadIdx.x;
    const int bbase = blockIdx.x * EPB;

    __shared__ uint32_t eds[EPB][NN];   // [e][n]: packed me[e][n+1][0..3]; stride 51 words
    __shared__ uint8_t  tre[EPB][52];   // Tree bytes; slot 51 = trash
    __shared__ uint8_t  rg [EPB][104];  // ring_idx pairs; offset 102 = trash

    {   // zero tre + rg with 16B stores
        const uint4 z = make_uint4(0, 0, 0, 0);
        uint4* t16 = (uint4*)&tre[0][0];
        for (int k = lane; k < EPB * 52 / 16; k += 64) t16[k] = z;
        uint4* r16 = (uint4*)&rg[0][0];
        for (int k = lane; k < EPB * 104 / 16; k += 64) r16[k] = z;
    }
    {   // stage + pack edges, coalesced
        const int4* e4 = (const int4*)edge + (size_t)bbase * A;
        #pragma unroll 10
        for (int k = 0; k < A; ++k) {
            const int gi = k * 64 + lane;
            const int4 v = e4[gi];
            const int e = gi / A;
            const int n = gi - A * e;
            eds[e][n] = (uint32_t)(v.x + 1) | ((uint32_t)(v.y + 1) << 8)
                      | ((uint32_t)(v.z + 1) << 16) | ((uint32_t)(v.w + 1) << 24);
        }
    }
    __syncthreads();

    uint64_t L = (((uint64_t)1 << NN) - 1) & ~(uint64_t)3;  // lnf: bits 0,1 cleared
    uint64_t V = (((uint64_t)1 << NN) - 1) & ~(uint64_t)1;  // nnv: bit 0 cleared
    int visiting = 1, nr = 0;
    bool done = false;

    for (int it = 0; it < A; ++it) {
        if (!done) {
            const uint32_t w = eds[lane][visiting - 1];
            const int n0 = w & 0xff, n1 = (w >> 8) & 0xff, n2 = (w >> 16) & 0xff, n3 = w >> 24;
            const uint64_t b0 = (uint64_t)1 << n0, b1 = (uint64_t)1 << n1;
            const uint64_t b2 = (uint64_t)1 << n2, b3 = (uint64_t)1 << n3;
            // found_at[d] = found_pre | duplicate-earlier-in-row (parallel, no serial L dep)
            const bool fa0 = (L & b0) == 0;
            const bool fa1 = ((L & b1) == 0) | (n1 == n0);
            const bool fa2 = ((L & b2) == 0) | (n2 == n0) | (n2 == n1);
            const bool fa3 = ((L & b3) == 0) | (n3 == n0) | (n3 == n1) | (n3 == n2);
            const bool c0 = fa0 & ((V & b0) != 0) & (n0 != 0);
            const bool c1 = fa1 & ((V & b1) != 0) & (n1 != 0);
            const bool c2 = fa2 & ((V & b2) != 0) & (n2 != 0);
            const bool c3 = fa3 & ((V & b3) != 0) & (n3 != 0);
            // Tree set-once (first unfound occurrence only; found/dup -> trash 51)
            tre[lane][fa0 ? 51 : n0] = (uint8_t)visiting;
            tre[lane][fa1 ? 51 : n1] = (uint8_t)visiting;
            tre[lane][fa2 ? 51 : n2] = (uint8_t)visiting;
            tre[lane][fa3 ? 51 : n3] = (uint8_t)visiting;
            // ring pushes in d-order (slot >= 51 dropped -> trash 102)
            *(uint16_t*)&rg[lane][(c0 & (nr < NN)) ? 2 * nr : 102] = (uint16_t)(visiting | (n0 << 8)); nr += c0;
            *(uint16_t*)&rg[lane][(c1 & (nr < NN)) ? 2 * nr : 102] = (uint16_t)(visiting | (n1 << 8)); nr += c1;
            *(uint16_t*)&rg[lane][(c2 & (nr < NN)) ? 2 * nr : 102] = (uint16_t)(visiting | (n2 << 8)); nr += c2;
            *(uint16_t*)&rg[lane][(c3 & (nr < NN)) ? 2 * nr : 102] = (uint16_t)(visiting | (n3 << 8)); nr += c3;
            L &= ~(b0 | b1 | b2 | b3);
            V &= ~((uint64_t)1 << visiting);
            const uint64_t M = V & ~L;
            if (M == 0) done = true;
            else visiting = (int)__builtin_ctzll(M);
        }
        if (__ballot(!done) == 0) break;
    }
    __syncthreads();

    // dump Tree (B,51) coalesced
    int* otree = out + (size_t)bbase * NN;
    #pragma unroll 3
    for (int k = 0; k < NN; ++k) {
        const int fi = k * 64 + lane;
        const int e = fi / NN, n = fi - NN * e;
        otree[fi] = tre[e][n];
    }
    // dump ring_idx (B,51,2) coalesced
    int2* oridx = (int2*)(out + (size_t)BATCH * NN) + (size_t)bbase * NN;
    #pragma unroll 3
    for (int k = 0; k < NN; ++k) {
        const int fi = k * 64 + lane;
        const int e = fi / NN, i = fi - NN * e;
        const uint16_t pv = *(const uint16_t*)&rg[e][2 * i];
        oridx[fi] = make_int2(pv & 0xff, pv >> 8);
    }
}

// ---------------- Kernel B: ring reconstruction, wave per element ----------------
// Per element: ancestor-set masks M[l] (uint64) + depth d[l] via 6 doubling
// steps, once. Per slot: meeting node m = unique lane with M[lane]==M[s0]&M[s1];
// t = d[s1]-d[m], u = d[s0]-d[m]; row is a depth-indexed scatter via ds_permute.
__global__ __launch_bounds__(WPB * 64)
void rings_kernel(int* __restrict__ out)
{
    const int lane = threadIdx.x & 63;
    const int wid  = threadIdx.x >> 6;
    const int b    = blockIdx.x * WPB + wid;

    const int*  tree_row = out + (size_t)b * NN;
    const int2* ridx_row = (const int2*)(out + (size_t)BATCH * NN) + (size_t)b * NN;
    int* orings = out + (size_t)BATCH * NN * 3 + (size_t)b * (MAXR * A);

    const int f = (lane < NN) ? tree_row[lane] : 0;  // lane l: Tree[l]
    int2 rid = make_int2(0, 0);
    if (lane < MAXR) rid = ridx_row[lane];

    // ancestor masks by pointer doubling: M[l] = {Tree^k(l) : k>=0} (incl. l, incl. 0)
    uint64_t M = ((uint64_t)1 << lane) | ((uint64_t)1 << f);
    int g = f;
    #pragma unroll
    for (int j = 0; j < 6; ++j) {
        const int lo = __builtin_amdgcn_ds_bpermute(g << 2, (int)(uint32_t)M);
        const int hi = __builtin_amdgcn_ds_bpermute(g << 2, (int)(M >> 32));
        M |= ((uint64_t)(uint32_t)hi << 32) | (uint32_t)lo;
        if (j < 5) g = __builtin_amdgcn_ds_bpermute(g << 2, g);
    }
    const int d   = __builtin_popcountll(M) - 1;  // depth (distance to node 0)
    const int Mlo = (int)(uint32_t)M, Mhi = (int)(M >> 32);

    for (int i = 0; i < MAXR; ++i) {
        int rowval = 0;
        const int s0 = __builtin_amdgcn_readlane(rid.x, i);
        if (s0 != 0) {  // slot active <=> i < num_rings
            const int s1 = __builtin_amdgcn_readlane(rid.y, i);
            const uint64_t set0 = ((uint64_t)(uint32_t)__builtin_amdgcn_readlane(Mhi, s0) << 32)
                                |  (uint32_t)__builtin_amdgcn_readlane(Mlo, s0);
            const uint64_t set1 = ((uint64_t)(uint32_t)__builtin_amdgcn_readlane(Mhi, s1) << 32)
                                |  (uint32_t)__builtin_amdgcn_readlane(Mlo, s1);
            const uint64_t common = set0 & set1;          // common-ancestor chain
            const uint64_t mv = __ballot(M == common);    // deepest common: M[m]==common
            const int m   = (int)__builtin_ctzll(mv);
            const int dm  = __builtin_amdgcn_readlane(d, m);
            const int ds0 = __builtin_amdgcn_readlane(d, s0);
            const int ds1 = __builtin_amdgcn_readlane(d, s1);
            const int t  = ds1 - dm;
            const int tu = t + (ds0 - dm);                // t + u
            const bool in1 = (set1 >> lane) & 1;
            const bool in0 = (set0 >> lane) & 1;
            // scatter: node `lane` -> its position in the ring row
            int pos = (in1 & (d >= dm)) ? (ds1 - d)           // seg1: path1[0..t]
                    : (in0 & (d >  dm)) ? (t + 1 + ds0 - d)   // seg2: s0-side
                    : 63;                                      // trash
            pos = pos < 63 ? pos : 63;
            const int pm = __builtin_amdgcn_ds_permute(pos << 2, lane);
            rowval = (lane == t + 1) ? s0 : (lane <= tu ? pm : 0);
        }
        if (lane < A) orings[i * A + lane] = rowval - 1;  // inactive rows -> -1
    }
}

extern "C" void kernel_launch(void* const* d_in, const int* in_sizes, int n_in,
                              void* d_out, int out_size, void* d_ws, size_t ws_size,
                              hipStream_t stream) {
    const int* edge = (const int*)d_in[0];
    int* out = (int*)d_out;

    hipLaunchKernelGGL(tree_kernel, dim3(BATCH / EPB), dim3(64), 0, stream, edge, out);
    hipLaunchKernelGGL(rings_kernel, dim3(BATCH / WPB), dim3(WPB * 64), 0, stream, out);
}

// Round 5
// 37.102 us; speedup vs baseline: 2.0619x; 1.1496x over previous
//
#include <hip/hip_runtime.h>
#include <stdint.h>

constexpr int BATCH = 16384;
constexpr int A     = 50;
constexpr int NN    = 51;   // A + 1
constexpr int MAXR  = 16;
constexpr int EPW   = 16;   // elements per wave in tree kernel (4 lanes/element)
constexpr int WPB   = 4;    // waves per block in rings kernel

// ---------------- Kernel A: quad-split tree construction ----------------
// 4 lanes per element: e = lane>>2, d = lane&3. All 4 lanes share the edge
// word w; each lane handles edge d's fa/c test + its 2 stores. Ring slot
// ordering across the quad via wave ballot + quad-prefix popcount.
// 1024 waves -> every SIMD on the chip gets one.
__global__ __launch_bounds__(64)
void tree_kernel(const int* __restrict__ edge, int* __restrict__ out)
{
    const int lane  = threadIdx.x;
    const int e     = lane >> 2;
    const int d     = lane & 3;
    const int bbase = blockIdx.x * EPW;

    __shared__ uint32_t eds[EPW][NN];   // packed me[e][n+1][0..3]
    __shared__ uint8_t  tre[EPW][52];   // Tree bytes; slot 51 = trash
    __shared__ uint8_t  rg [EPW][104];  // ring_idx pairs; offset 102 = trash

    {   // zero tre + rg
        const uint4 z = make_uint4(0, 0, 0, 0);
        uint4* t16 = (uint4*)&tre[0][0];
        if (lane < EPW * 52 / 16) t16[lane] = z;
        uint4* r16 = (uint4*)&rg[0][0];
        for (int k = lane; k < EPW * 104 / 16; k += 64) r16[k] = z;
    }
    {   // stage + pack edges (16 elements x 50 int4), coalesced
        const int4* e4 = (const int4*)edge + (size_t)bbase * A;
        #pragma unroll
        for (int k = 0; k < 13; ++k) {
            const int gi = k * 64 + lane;
            if (gi < EPW * A) {
                const int4 v = e4[gi];
                const int el = gi / A, n = gi - A * el;
                eds[el][n] = (uint32_t)(v.x + 1) | ((uint32_t)(v.y + 1) << 8)
                           | ((uint32_t)(v.z + 1) << 16) | ((uint32_t)(v.w + 1) << 24);
            }
        }
    }
    __syncthreads();

    uint64_t L = (((uint64_t)1 << NN) - 1) & ~(uint64_t)3;  // lnf: bits 0,1 cleared
    uint64_t V = (((uint64_t)1 << NN) - 1) & ~(uint64_t)1;  // nnv: bit 0 cleared
    int visiting = 1, nr = 0;
    bool done = false;
    const int dmaskc = (1 << d) - 1;   // bits of quad-mates with lower d

    for (int it = 0; it < A; ++it) {
        bool c = false; int myn = 0;
        if (!done) {
            const uint32_t w = eds[e][visiting - 1];
            const int n0 = w & 0xff, n1 = (w >> 8) & 0xff, n2 = (w >> 16) & 0xff, n3 = w >> 24;
            myn = (w >> (8 * d)) & 0xff;
            const uint64_t bu = ((uint64_t)1 << n0) | ((uint64_t)1 << n1)
                              | ((uint64_t)1 << n2) | ((uint64_t)1 << n3);
            const uint64_t bm = (uint64_t)1 << myn;
            // duplicate earlier in this row -> counts as already-found
            const bool dup = ((d > 0) & (myn == n0)) | ((d > 1) & (myn == n1)) | ((d > 2) & (myn == n2));
            const bool fa  = ((L & bm) == 0) | dup;              // found-at-my-turn
            c = fa & ((V & bm) != 0) & (myn != 0);               // cycle edge
            tre[e][fa ? 51 : myn] = (uint8_t)visiting;           // Tree set-once
            L &= ~bu;
        }
        const uint64_t Bc = __ballot(c);          // full-wave; done lanes contribute 0
        if (!done) {
            const uint32_t qb = (uint32_t)(Bc >> (lane & 60)) & 0xfu;  // my quad's c bits
            const int slot = nr + __builtin_popcount(qb & dmaskc);     // d-ordered slot
            *(uint16_t*)&rg[e][(c & (slot < NN)) ? 2 * slot : 102] =
                (uint16_t)(visiting | (myn << 8));
            nr += __builtin_popcount(qb);
            V &= ~((uint64_t)1 << visiting);
            const uint64_t M = V & ~L;
            if (M == 0) done = true;
            else visiting = (int)__builtin_ctzll(M);
        }
        if (__ballot(!done) == 0) break;
    }
    __syncthreads();

    // dump Tree (16x51 ints) coalesced
    int* otree = out + (size_t)bbase * NN;
    #pragma unroll
    for (int k = 0; k < 13; ++k) {
        const int fi = k * 64 + lane;
        if (fi < EPW * NN) { const int el = fi / NN, n = fi - NN * el; otree[fi] = tre[el][n]; }
    }
    // dump ring_idx (16x51 int2) coalesced
    int2* oridx = (int2*)(out + (size_t)BATCH * NN) + (size_t)bbase * NN;
    #pragma unroll
    for (int k = 0; k < 13; ++k) {
        const int fi = k * 64 + lane;
        if (fi < EPW * NN) {
            const int el = fi / NN, i = fi - NN * el;
            const uint16_t pv = *(const uint16_t*)&rg[el][2 * i];
            oridx[fi] = make_int2(pv & 0xff, pv >> 8);
        }
    }
}

// ---------------- Kernel B: ring reconstruction, wave per element ----------------
// Ancestor masks M[l] by doubling (verified). Slot prep fully parallel:
// set0/set1 for all 16 slots via 4 bpermutes; depths via popcount
// (common = M[LCA] => dm = popc(common)-1). Active-prefix loop + vectorized
// -1 tail fill.
__global__ __launch_bounds__(WPB * 64)
void rings_kernel(int* __restrict__ out)
{
    const int lane = threadIdx.x & 63;
    const int wid  = threadIdx.x >> 6;
    const int b    = blockIdx.x * WPB + wid;

    const int*  tree_row = out + (size_t)b * NN;
    const int2* ridx_row = (const int2*)(out + (size_t)BATCH * NN) + (size_t)b * NN;
    int* orings = out + (size_t)BATCH * NN * 3 + (size_t)b * (MAXR * A);

    const int f = (lane < NN) ? tree_row[lane] : 0;  // lane l: Tree[l]
    int2 rid = make_int2(0, 0);
    if (lane < MAXR) rid = ridx_row[lane];

    // ancestor masks: M[l] = {Tree^k(l) : k>=0} (incl. l and 0)
    uint64_t M = ((uint64_t)1 << lane) | ((uint64_t)1 << f);
    int g = f;
    #pragma unroll
    for (int j = 0; j < 6; ++j) {
        const int lo = __builtin_amdgcn_ds_bpermute(g << 2, (int)(uint32_t)M);
        const int hi = __builtin_amdgcn_ds_bpermute(g << 2, (int)(M >> 32));
        M |= ((uint64_t)(uint32_t)hi << 32) | (uint32_t)lo;
        if (j < 5) g = __builtin_amdgcn_ds_bpermute(g << 2, g);
    }
    const int d   = __builtin_popcountll(M) - 1;   // depth
    const int Mlo = (int)(uint32_t)M, Mhi = (int)(M >> 32);

    // per-slot prep, parallel across lanes 0..15 (others harmless)
    const int a0 = rid.x << 2, a1 = rid.y << 2;
    const uint64_t set0 = ((uint64_t)(uint32_t)__builtin_amdgcn_ds_bpermute(a0, Mhi) << 32)
                        |  (uint32_t)__builtin_amdgcn_ds_bpermute(a0, Mlo);
    const uint64_t set1 = ((uint64_t)(uint32_t)__builtin_amdgcn_ds_bpermute(a1, Mhi) << 32)
                        |  (uint32_t)__builtin_amdgcn_ds_bpermute(a1, Mlo);
    const int dm  = __builtin_popcountll(set0 & set1) - 1;  // depth of LCA
    const int ds0 = __builtin_popcountll(set0) - 1;
    const int ds1 = __builtin_popcountll(set1) - 1;
    const int nact = __popcll(__ballot((lane < MAXR) && (rid.x != 0)));

    const int s0lo = (int)(uint32_t)set0, s0hi = (int)(set0 >> 32);
    const int s1lo = (int)(uint32_t)set1, s1hi = (int)(set1 >> 32);

    for (int i = 0; i < nact; ++i) {
        const uint64_t set0b = ((uint64_t)(uint32_t)__builtin_amdgcn_readlane(s0hi, i) << 32)
                             |  (uint32_t)__builtin_amdgcn_readlane(s0lo, i);
        const uint64_t set1b = ((uint64_t)(uint32_t)__builtin_amdgcn_readlane(s1hi, i) << 32)
                             |  (uint32_t)__builtin_amdgcn_readlane(s1lo, i);
        const int dmb  = __builtin_amdgcn_readlane(dm,  i);
        const int ds0b = __builtin_amdgcn_readlane(ds0, i);
        const int ds1b = __builtin_amdgcn_readlane(ds1, i);
        const int s0b  = __builtin_amdgcn_readlane(rid.x, i);
        const int tb = ds1b - dmb, tub = tb + ds0b - dmb;

        const bool on1 = ((set1b >> lane) & 1) && (d >= dmb);  // s1-chain, depth>=dm
        const bool on0 = ((set0b >> lane) & 1) && (d >  dmb);  // s0-chain, below LCA
        int pos = on1 ? (ds1b - d) : on0 ? (tb + 1 + ds0b - d) : 63;
        pos = pos < 63 ? pos : 63;
        const int pm = __builtin_amdgcn_ds_permute(pos << 2, lane);  // node -> position
        const int rowval = (lane == tb + 1) ? s0b : (lane <= tub ? pm : 0);
        if (lane < A) orings[i * A + lane] = rowval - 1;
    }

    // tail fill: rows nact..15 are all -1; contiguous region, int2-aligned
    {
        const int startw = nact * A;                 // even -> 8B aligned
        int2* p2 = (int2*)(orings + startw);
        const int n2 = (MAXR * A - startw) >> 1;
        for (int k = lane; k < n2; k += 64) p2[k] = make_int2(-1, -1);
    }
}

extern "C" void kernel_launch(void* const* d_in, const int* in_sizes, int n_in,
                              void* d_out, int out_size, void* d_ws, size_t ws_size,
                              hipStream_t stream) {
    const int* edge = (const int*)d_in[0];
    int* out = (int*)d_out;

    hipLaunchKernelGGL(tree_kernel, dim3(BATCH / EPW), dim3(64), 0, stream, edge, out);
    hipLaunchKernelGGL(rings_kernel, dim3(BATCH / WPB), dim3(WPB * 64), 0, stream, out);
}

// Round 6
// 29.731 us; speedup vs baseline: 2.5730x; 1.2479x over previous
//
#include <hip/hip_runtime.h>
#include <stdint.h>

constexpr int BATCH = 16384;
constexpr int A     = 50;
constexpr int NN    = 51;   // A + 1
constexpr int MAXR  = 16;
constexpr int EPW   = 8;    // elements per wave (8 lanes per element)
constexpr int WPB   = 4;    // waves per block

// Fused kernel: each wave is fully self-contained — phase A builds trees for
// its 8 elements (octet-split, prefetch-pipelined), phase B reconstructs rings
// for the same 8 elements from the wave-private LDS slice. No __syncthreads.
__global__ __launch_bounds__(WPB * 64)
void fused_kernel(const int* __restrict__ edge, int* __restrict__ out)
{
    const int lane  = threadIdx.x & 63;
    const int wid   = threadIdx.x >> 6;
    const int gbase = (blockIdx.x * WPB + wid) * EPW;  // this wave's first element

    __shared__ uint32_t eds[WPB][EPW][NN];   // packed me[e][n+1][0..3]
    __shared__ uint8_t  tre[WPB][EPW][52];   // Tree bytes; slot 51 = trash
    __shared__ uint8_t  rg [WPB][EPW][104];  // ring_idx pairs; offset 102 = trash

    {   // zero tre + rg (wave-private slices)
        const uint4 z = make_uint4(0, 0, 0, 0);
        uint4* t16 = (uint4*)&tre[wid][0][0];           // 8*52/16 = 26
        if (lane < 26) t16[lane] = z;
        uint4* r16 = (uint4*)&rg[wid][0][0];            // 8*104/16 = 52
        if (lane < 52) r16[lane] = z;
    }
    {   // stage + pack this wave's edges: 8 elements x 50 int4, coalesced
        const int4* e4 = (const int4*)edge + (size_t)gbase * A;
        #pragma unroll
        for (int k = 0; k < 7; ++k) {
            const int gi = k * 64 + lane;
            if (gi < EPW * A) {
                const int4 v = e4[gi];
                const int el = gi / A, n = gi - A * el;
                eds[wid][el][n] = (uint32_t)(v.x + 1) | ((uint32_t)(v.y + 1) << 8)
                                | ((uint32_t)(v.z + 1) << 16) | ((uint32_t)(v.w + 1) << 24);
            }
        }
    }
    // (same-wave LDS RAW: hardware lgkmcnt ordering, no barrier needed)

    // ---------------- phase A: tree construction ----------------
    const int  e  = lane >> 3;    // element within wave
    const int  d8 = lane & 7;
    const int  d  = d8 & 3;       // edge index this lane mirrors
    const bool hi = d8 >= 4;      // hi half of octet: does the rg store

    uint64_t L = (((uint64_t)1 << NN) - 1) & ~(uint64_t)3;  // lnf: 0,1 found
    uint64_t V = (((uint64_t)1 << NN) - 1) & ~(uint64_t)1;  // nnv: 0 visited
    uint64_t M = 2;               // found & not visited = {1}
    int visiting = 1, nr = 0;
    uint32_t w = eds[wid][e][0];  // prefetched row of node 1

    #pragma unroll 1
    for (int it = 0; it < A; ++it) {
        const int n0 = w & 0xff, n1 = (w >> 8) & 0xff, n2 = (w >> 16) & 0xff, n3 = w >> 24;
        const uint64_t bu = ((uint64_t)1 << n0) | ((uint64_t)1 << n1)
                          | ((uint64_t)1 << n2) | ((uint64_t)1 << n3);
        const int myn = (w >> (8 * d)) & 0xff;
        const uint64_t bm = (uint64_t)1 << myn;
        // --- next-visit precompute + prefetch (overlaps bookkeeping) ---
        const uint64_t visbit = (uint64_t)1 << visiting;
        const uint64_t Mn = (M | (V & bu)) & ~visbit;   // next found&!visited set
        const bool dn = (Mn == 0);
        const uint64_t Msafe = dn ? (uint64_t)2 : Mn;
        const int nv = (int)__builtin_ctzll(Msafe);     // next visiting (dummy 1 if done)
        const uint32_t wn = eds[wid][e][nv - 1];        // prefetch next edge row
        // --- bookkeeping with OLD L,V ---
        const bool dup = ((d > 0) & (myn == n0)) | ((d > 1) & (myn == n1)) | ((d > 2) & (myn == n2));
        const bool fa  = ((L & bm) == 0) | dup;         // found at my edge's turn
        const bool cf  = fa & ((V & bm) != 0) & (myn != 0);   // cycle edge
        const bool cb  = cf & !hi;                      // ballot only low half
        const uint64_t Bc = __ballot(cb);
        const uint32_t qb = (uint32_t)(Bc >> (lane & 56)) & 0xfu;  // my octet's bits
        const int slot = nr + __builtin_popcount(qb & ((1u << d) - 1));
        nr += __builtin_popcount(qb);
        // lanes 0-3: Tree set-once; lanes 4-7: ring slot push (trash-addressed off)
        tre[wid][e][(fa | hi) ? 51 : myn] = (uint8_t)visiting;
        *(uint16_t*)&rg[wid][e][(cf & hi & (slot < NN)) ? 2 * slot : 102] =
            (uint16_t)(visiting | (myn << 8));
        L &= ~bu;
        V &= ~visbit;
        M = Mn; visiting = nv;
        w = dn ? 0u : wn;   // done lanes idle harmlessly (myn=0 -> no cycles, trash stores)
        if (__ballot(!dn) == 0) break;
    }

    // ---------------- phase B: rings for this wave's 8 elements ----------------
    int*  otree = out;                                   // (B,51)
    int2* oridx = (int2*)(out + (size_t)BATCH * NN);     // (B,51) of int2

    #pragma unroll 1
    for (int e2 = 0; e2 < EPW; ++e2) {
        const int b = gbase + e2;
        const uint32_t pv = (lane < NN) ? *(const uint16_t*)&rg[wid][e2][2 * lane] : 0;
        const int f = (lane < NN) ? (int)tre[wid][e2][lane] : 0;   // lane l: Tree[l]
        if (lane < NN) {
            otree[(size_t)b * NN + lane] = f;
            oridx[(size_t)b * NN + lane] = make_int2((int)(pv & 0xff), (int)(pv >> 8));
        }
        const int r0 = (int)(pv & 0xff), r1 = (int)(pv >> 8);  // ring_idx slots (lanes<16)

        // ancestor masks: Mk[l] = {Tree^k(l) : k>=0} (incl. l and 0)
        uint64_t Mk = ((uint64_t)1 << lane) | ((uint64_t)1 << f);
        int g = f;
        #pragma unroll
        for (int j = 0; j < 6; ++j) {
            const int lo = __builtin_amdgcn_ds_bpermute(g << 2, (int)(uint32_t)Mk);
            const int hh = __builtin_amdgcn_ds_bpermute(g << 2, (int)(Mk >> 32));
            Mk |= ((uint64_t)(uint32_t)hh << 32) | (uint32_t)lo;
            if (j < 5) g = __builtin_amdgcn_ds_bpermute(g << 2, g);
        }
        const int dep = __builtin_popcountll(Mk) - 1;    // depth (distance to node 0)
        const int Mlo = (int)(uint32_t)Mk, Mhi = (int)(Mk >> 32);

        // per-slot prep, parallel across lanes 0..15
        const int a0 = r0 << 2, a1 = r1 << 2;
        const uint64_t set0 = ((uint64_t)(uint32_t)__builtin_amdgcn_ds_bpermute(a0, Mhi) << 32)
                            |  (uint32_t)__builtin_amdgcn_ds_bpermute(a0, Mlo);
        const uint64_t set1 = ((uint64_t)(uint32_t)__builtin_amdgcn_ds_bpermute(a1, Mhi) << 32)
                            |  (uint32_t)__builtin_amdgcn_ds_bpermute(a1, Mlo);
        const int dm  = __builtin_popcountll(set0 & set1) - 1;  // LCA depth
        const int ds0 = __builtin_popcountll(set0) - 1;
        const int ds1 = __builtin_popcountll(set1) - 1;
        const int nact = __popcll(__ballot((lane < MAXR) && (r0 != 0)));

        const int s0lo = (int)(uint32_t)set0, s0hi = (int)(set0 >> 32);
        const int s1lo = (int)(uint32_t)set1, s1hi = (int)(set1 >> 32);
        int* orings = out + (size_t)BATCH * NN * 3 + (size_t)b * (MAXR * A);

        for (int i = 0; i < nact; ++i) {
            const uint64_t set0b = ((uint64_t)(uint32_t)__builtin_amdgcn_readlane(s0hi, i) << 32)
                                 |  (uint32_t)__builtin_amdgcn_readlane(s0lo, i);
            const uint64_t set1b = ((uint64_t)(uint32_t)__builtin_amdgcn_readlane(s1hi, i) << 32)
                                 |  (uint32_t)__builtin_amdgcn_readlane(s1lo, i);
            const int dmb  = __builtin_amdgcn_readlane(dm,  i);
            const int ds0b = __builtin_amdgcn_readlane(ds0, i);
            const int ds1b = __builtin_amdgcn_readlane(ds1, i);
            const int s0b  = __builtin_amdgcn_readlane(r0,  i);
            const int tb = ds1b - dmb, tub = tb + ds0b - dmb;

            const bool on1 = ((set1b >> lane) & 1) && (dep >= dmb);
            const bool on0 = ((set0b >> lane) & 1) && (dep >  dmb);
            int pos = on1 ? (ds1b - dep) : on0 ? (tb + 1 + ds0b - dep) : 63;
            pos = pos < 63 ? pos : 63;
            const int pm = __builtin_amdgcn_ds_permute(pos << 2, lane);  // node -> position
            const int rowval = (lane == tb + 1) ? s0b : (lane <= tub ? pm : 0);
            if (lane < A) orings[i * A + lane] = rowval - 1;
        }
        // tail fill: rows nact..15 are all -1 (contiguous, 8B aligned)
        {
            const int startw = nact * A;
            int2* p2 = (int2*)(orings + startw);
            const int n2 = (MAXR * A - startw) >> 1;
            for (int k = lane; k < n2; k += 64) p2[k] = make_int2(-1, -1);
        }
    }
}

extern "C" void kernel_launch(void* const* d_in, const int* in_sizes, int n_in,
                              void* d_out, int out_size, void* d_ws, size_t ws_size,
                              hipStream_t stream) {
    const int* edge = (const int*)d_in[0];
    int* out = (int*)d_out;
    hipLaunchKernelGGL(fused_kernel, dim3(BATCH / (EPW * WPB)), dim3(WPB * 64), 0, stream,
                       edge, out);
}